// Round 4
// baseline (390.098 us; speedup 1.0000x reference)
//
#include <hip/hip_runtime.h>
#include <math.h>

#define BATCH 32
#define NC    1024
#define NHID  512
#define NH    56
#define NW    56
#define HWSZ  3136   // 56*56
#define HW4   784    // HWSZ/4

// ---------------------------------------------------------------------------
// Kernel 1: global average pool over (H,W). One block per (b,c) row.
// ---------------------------------------------------------------------------
__global__ __launch_bounds__(256) void gap_kernel(const float* __restrict__ x,
                                                  float* __restrict__ y) {
    const int row = blockIdx.x;  // b*NC + c
    const float4* xr = (const float4*)(x + (size_t)row * HWSZ);
    const int t = threadIdx.x;

    float s = 0.f;
#pragma unroll
    for (int it = 0; it < 4; ++it) {
        int idx = t + it * 256;
        if (idx < HW4) {
            float4 v = xr[idx];
            s += v.x + v.y + v.z + v.w;
        }
    }
    // wave64 reduce
    for (int off = 32; off > 0; off >>= 1) s += __shfl_down(s, off);
    __shared__ float wsum[4];
    const int lane = t & 63, wid = t >> 6;
    if (lane == 0) wsum[wid] = s;
    __syncthreads();
    if (t == 0) {
        y[row] = (wsum[0] + wsum[1] + wsum[2] + wsum[3]) * (1.0f / 3136.0f);
    }
}

// ---------------------------------------------------------------------------
// Kernel 2: MLP + attention map. One block per batch element.
// h = gelu(y@W1); yp = gelu(h@W2); A = yp@WA+bA; Bv = yp@WB+bB;
// attn[b,i,j] = sigmoid(A[i]*Bv[j])
// ---------------------------------------------------------------------------
__device__ __forceinline__ float gelu_exact(float x) {
    return 0.5f * x * (1.0f + erff(x * 0.7071067811865476f));
}

__global__ __launch_bounds__(256) void mlp_kernel(
    const float* __restrict__ y,  const float* __restrict__ W1,
    const float* __restrict__ W2, const float* __restrict__ WA,
    const float* __restrict__ bA, const float* __restrict__ WB,
    const float* __restrict__ bB, float* __restrict__ attn) {
    const int b = blockIdx.x;
    const int t = threadIdx.x;

    __shared__ float sy[NC];
    __shared__ float sh[NHID];
    __shared__ float syp[NC];
    __shared__ float sA[NH];
    __shared__ float sB[NW];

    for (int i = t; i < NC; i += 256) sy[i] = y[b * NC + i];
    __syncthreads();

    // h = gelu(y @ W1): W1 is (NC, NHID) row-major -> coalesced over j
    for (int j = t; j < NHID; j += 256) {
        float acc = 0.f;
        for (int c = 0; c < NC; ++c) acc += sy[c] * W1[c * NHID + j];
        sh[j] = gelu_exact(acc);
    }
    __syncthreads();

    // yp = gelu(h @ W2): W2 is (NHID, NC)
    for (int c = t; c < NC; c += 256) {
        float acc = 0.f;
        for (int j = 0; j < NHID; ++j) acc += sh[j] * W2[j * NC + c];
        syp[c] = gelu_exact(acc);
    }
    __syncthreads();

    // A = yp @ WA + bA (WA is (NC, NH)); Bv = yp @ WB + bB (WB is (NC, NW))
    if (t < NH) {
        float acc = bA[t];
        for (int c = 0; c < NC; ++c) acc += syp[c] * WA[c * NH + t];
        sA[t] = acc;
    } else if (t >= 64 && t < 64 + NW) {
        const int j = t - 64;
        float acc = bB[j];
        for (int c = 0; c < NC; ++c) acc += syp[c] * WB[c * NW + j];
        sB[j] = acc;
    }
    __syncthreads();

    // attn[i][j] = sigmoid(A[i] * Bv[j])
    for (int idx = t; idx < HWSZ; idx += 256) {
        const int i = idx / NW;
        const int j = idx - i * NW;
        const float v = sA[i] * sB[j];
        attn[b * HWSZ + idx] = 1.0f / (1.0f + expf(-v));
    }
}

// ---------------------------------------------------------------------------
// Kernel 3: broadcast attn (b, 56, 56) across 1024 channels.
// One block handles (b, 8 consecutive channels); attn row cached in regs.
// ---------------------------------------------------------------------------
__global__ __launch_bounds__(256) void bcast_kernel(const float* __restrict__ attn,
                                                    float* __restrict__ out) {
    const int blk = blockIdx.x;
    const int b = blk >> 7;          // 128 chunks of 8 channels per batch
    const int cchunk = blk & 127;
    const int t = threadIdx.x;

    const float4* ar = (const float4*)(attn + (size_t)b * HWSZ);
    float4 v[4];
#pragma unroll
    for (int it = 0; it < 4; ++it) {
        int idx = t + it * 256;
        v[it] = (idx < HW4) ? ar[idx] : make_float4(0.f, 0.f, 0.f, 0.f);
    }

    const size_t base = ((size_t)b * NC + (size_t)cchunk * 8) * HWSZ;
#pragma unroll
    for (int c = 0; c < 8; ++c) {
        float4* orow = (float4*)(out + base + (size_t)c * HWSZ);
#pragma unroll
        for (int it = 0; it < 4; ++it) {
            int idx = t + it * 256;
            if (idx < HW4) orow[idx] = v[it];
        }
    }
}

// ---------------------------------------------------------------------------
extern "C" void kernel_launch(void* const* d_in, const int* in_sizes, int n_in,
                              void* d_out, int out_size, void* d_ws, size_t ws_size,
                              hipStream_t stream) {
    const float* x  = (const float*)d_in[0];
    const float* W1 = (const float*)d_in[1];
    const float* W2 = (const float*)d_in[2];
    const float* WA = (const float*)d_in[3];
    const float* bA = (const float*)d_in[4];
    const float* WB = (const float*)d_in[5];
    const float* bB = (const float*)d_in[6];
    float* out = (float*)d_out;

    float* y    = (float*)d_ws;          // BATCH*NC floats = 128 KiB
    float* attn = y + BATCH * NC;        // BATCH*HWSZ floats = 392 KiB

    gap_kernel<<<BATCH * NC, 256, 0, stream>>>(x, y);
    mlp_kernel<<<BATCH, 256, 0, stream>>>(y, W1, W2, WA, bA, WB, bB, attn);
    bcast_kernel<<<BATCH * (NC / 8), 256, 0, stream>>>(attn, out);
}

// Round 5
// 215.803 us; speedup vs baseline: 1.8077x; 1.8077x over previous
//
#include <hip/hip_runtime.h>
#include <math.h>

#define BATCH 32
#define NC    1024
#define NHID  512
#define NH    56
#define NW    56
#define HWSZ  3136   // 56*56
#define HW4   784    // HWSZ/4

__device__ __forceinline__ float gelu_exact(float x) {
    return 0.5f * x * (1.0f + erff(x * 0.7071067811865476f));
}
__device__ __forceinline__ float sigmoidf_(float v) {
    return 1.0f / (1.0f + expf(-v));
}

// ---------------------------------------------------------------------------
// Kernel 1: global average pool over (H,W). One block per (b,c) row.
// ---------------------------------------------------------------------------
__global__ __launch_bounds__(256) void gap_kernel(const float* __restrict__ x,
                                                  float* __restrict__ y) {
    const int row = blockIdx.x;  // b*NC + c
    const float4* xr = (const float4*)(x + (size_t)row * HWSZ);
    const int t = threadIdx.x;

    float s = 0.f;
#pragma unroll
    for (int it = 0; it < 4; ++it) {
        int idx = t + it * 256;
        if (idx < HW4) {
            float4 v = xr[idx];
            s += v.x + v.y + v.z + v.w;
        }
    }
    for (int off = 32; off > 0; off >>= 1) s += __shfl_down(s, off);
    __shared__ float wsum[4];
    const int lane = t & 63, wid = t >> 6;
    if (lane == 0) wsum[wid] = s;
    __syncthreads();
    if (t == 0) {
        y[row] = (wsum[0] + wsum[1] + wsum[2] + wsum[3]) * (1.0f / 3136.0f);
    }
}

// ---------------------------------------------------------------------------
// Kernel 2: h = gelu(y @ W1).  Block = (jc, b): 64 output cols, 4-way split-K.
// W1 is (NC, NHID) row-major; lanes read 64 consecutive j -> coalesced.
// ---------------------------------------------------------------------------
__global__ __launch_bounds__(256) void fc1_kernel(const float* __restrict__ y,
                                                  const float* __restrict__ W1,
                                                  float* __restrict__ h) {
    const int jc = blockIdx.x;   // 0..7
    const int b  = blockIdx.y;   // 0..31
    const int t  = threadIdx.x;

    __shared__ float sy[NC];
    __shared__ float part[256];
    for (int i = t; i < NC; i += 256) sy[i] = y[b * NC + i];
    __syncthreads();

    const int j  = jc * 64 + (t & 63);
    const int ks = (t >> 6) * 256;           // 4 K-slices of 256
    const float* w = W1 + (size_t)ks * NHID + j;

    float a0 = 0.f, a1 = 0.f, a2 = 0.f, a3 = 0.f;
    for (int c = 0; c < 256; c += 4) {
        a0 += sy[ks + c + 0] * w[(size_t)(c + 0) * NHID];
        a1 += sy[ks + c + 1] * w[(size_t)(c + 1) * NHID];
        a2 += sy[ks + c + 2] * w[(size_t)(c + 2) * NHID];
        a3 += sy[ks + c + 3] * w[(size_t)(c + 3) * NHID];
    }
    part[t] = (a0 + a1) + (a2 + a3);
    __syncthreads();
    if (t < 64) {
        float v = part[t] + part[t + 64] + part[t + 128] + part[t + 192];
        h[b * NHID + jc * 64 + t] = gelu_exact(v);
    }
}

// ---------------------------------------------------------------------------
// Kernel 3: yp = gelu(h @ W2).  Block = (cc, b): 64 output cols, 4-way split-K.
// W2 is (NHID, NC) row-major.
// ---------------------------------------------------------------------------
__global__ __launch_bounds__(256) void fc2_kernel(const float* __restrict__ h,
                                                  const float* __restrict__ W2,
                                                  float* __restrict__ yp) {
    const int cc = blockIdx.x;   // 0..15
    const int b  = blockIdx.y;
    const int t  = threadIdx.x;

    __shared__ float sh[NHID];
    __shared__ float part[256];
    for (int i = t; i < NHID; i += 256) sh[i] = h[b * NHID + i];
    __syncthreads();

    const int c  = cc * 64 + (t & 63);
    const int js = (t >> 6) * 128;           // 4 K-slices of 128
    const float* w = W2 + (size_t)js * NC + c;

    float a0 = 0.f, a1 = 0.f, a2 = 0.f, a3 = 0.f;
    for (int jj = 0; jj < 128; jj += 4) {
        a0 += sh[js + jj + 0] * w[(size_t)(jj + 0) * NC];
        a1 += sh[js + jj + 1] * w[(size_t)(jj + 1) * NC];
        a2 += sh[js + jj + 2] * w[(size_t)(jj + 2) * NC];
        a3 += sh[js + jj + 3] * w[(size_t)(jj + 3) * NC];
    }
    part[t] = (a0 + a1) + (a2 + a3);
    __syncthreads();
    if (t < 64) {
        float v = part[t] + part[t + 64] + part[t + 128] + part[t + 192];
        yp[b * NC + cc * 64 + t] = gelu_exact(v);
    }
}

// ---------------------------------------------------------------------------
// Kernel 4: A = yp@WA+bA, Bv = yp@WB+bB, attn = sigmoid(A[i]*Bv[j]).
// One block per batch; split-K over C for both A and B.
// ---------------------------------------------------------------------------
__global__ __launch_bounds__(256) void attn_kernel(
    const float* __restrict__ yp, const float* __restrict__ WA,
    const float* __restrict__ bA, const float* __restrict__ WB,
    const float* __restrict__ bB, float* __restrict__ attn) {
    const int b = blockIdx.x;
    const int t = threadIdx.x;

    __shared__ float sp[NC];
    __shared__ float partA[256];
    __shared__ float partB[256];
    __shared__ float sA[64];
    __shared__ float sB[64];

    for (int i = t; i < NC; i += 256) sp[i] = yp[b * NC + i];
    __syncthreads();

    const int i  = t & 63;
    const int ks = (t >> 6) * 256;
    float accA = 0.f, accB = 0.f;
    if (i < NH) {
        const float* wa = WA + (size_t)ks * NH + i;
        for (int c = 0; c < 256; ++c) accA += sp[ks + c] * wa[(size_t)c * NH];
    }
    if (i < NW) {
        const float* wb = WB + (size_t)ks * NW + i;
        for (int c = 0; c < 256; ++c) accB += sp[ks + c] * wb[(size_t)c * NW];
    }
    partA[t] = accA;
    partB[t] = accB;
    __syncthreads();
    if (t < 64) {
        if (t < NH) sA[t] = bA[t] + partA[t] + partA[t + 64] + partA[t + 128] + partA[t + 192];
        if (t < NW) sB[t] = bB[t] + partB[t] + partB[t + 64] + partB[t + 128] + partB[t + 192];
    }
    __syncthreads();

    for (int idx = t; idx < HWSZ; idx += 256) {
        const int r = idx / NW;
        const int c = idx - r * NW;
        attn[b * HWSZ + idx] = sigmoidf_(sA[r] * sB[c]);
    }
}

// ---------------------------------------------------------------------------
// Kernel 5: broadcast attn (b, 56, 56) across 1024 channels.
// ---------------------------------------------------------------------------
__global__ __launch_bounds__(256) void bcast_kernel(const float* __restrict__ attn,
                                                    float* __restrict__ out) {
    const int blk = blockIdx.x;
    const int b = blk >> 7;          // 128 chunks of 8 channels per batch
    const int cchunk = blk & 127;
    const int t = threadIdx.x;

    const float4* ar = (const float4*)(attn + (size_t)b * HWSZ);
    float4 v[4];
#pragma unroll
    for (int it = 0; it < 4; ++it) {
        int idx = t + it * 256;
        v[it] = (idx < HW4) ? ar[idx] : make_float4(0.f, 0.f, 0.f, 0.f);
    }

    const size_t base = ((size_t)b * NC + (size_t)cchunk * 8) * HWSZ;
#pragma unroll
    for (int c = 0; c < 8; ++c) {
        float4* orow = (float4*)(out + base + (size_t)c * HWSZ);
#pragma unroll
        for (int it = 0; it < 4; ++it) {
            int idx = t + it * 256;
            if (idx < HW4) orow[idx] = v[it];
        }
    }
}

// ---------------------------------------------------------------------------
extern "C" void kernel_launch(void* const* d_in, const int* in_sizes, int n_in,
                              void* d_out, int out_size, void* d_ws, size_t ws_size,
                              hipStream_t stream) {
    const float* x  = (const float*)d_in[0];
    const float* W1 = (const float*)d_in[1];
    const float* W2 = (const float*)d_in[2];
    const float* WA = (const float*)d_in[3];
    const float* bA = (const float*)d_in[4];
    const float* WB = (const float*)d_in[5];
    const float* bB = (const float*)d_in[6];
    float* out = (float*)d_out;

    // ws layout (floats): y/yp alias (y dead after fc1, yp written by fc2)
    float* y    = (float*)d_ws;                  // BATCH*NC    = 32K floats
    float* yp   = y;                             // alias — y dead after fc1
    float* h    = y + BATCH * NC;                // BATCH*NHID  = 16K floats
    float* attn = h + BATCH * NHID;              // BATCH*HWSZ  = 100K floats
                                                 // total ≈ 595 KiB

    gap_kernel<<<BATCH * NC, 256, 0, stream>>>(x, y);
    fc1_kernel<<<dim3(NHID / 64, BATCH), 256, 0, stream>>>(y, W1, h);
    fc2_kernel<<<dim3(NC / 64, BATCH), 256, 0, stream>>>(h, W2, yp);
    attn_kernel<<<BATCH, 256, 0, stream>>>(yp, WA, bA, WB, bB, attn);
    bcast_kernel<<<BATCH * (NC / 8), 256, 0, stream>>>(attn, out);
}

// Round 7
// 181.496 us; speedup vs baseline: 2.1494x; 1.1890x over previous
//
#include <hip/hip_runtime.h>
#include <math.h>

#define BATCH 32
#define NC    1024
#define NHID  512
#define NH    56
#define NW    56
#define HWSZ  3136   // 56*56
#define HW4   784    // HWSZ/4 (= 56 rows * 14 float4/row)

typedef float nfloat4 __attribute__((ext_vector_type(4)));

__device__ __forceinline__ float gelu_exact(float x) {
    return 0.5f * x * (1.0f + erff(x * 0.7071067811865476f));
}

// ---------------------------------------------------------------------------
// Kernel 1: GAP. One WAVE per (b,c) row — no LDS, no barriers.
// 784 float4 per row = 12*64 + 16.
// ---------------------------------------------------------------------------
__global__ __launch_bounds__(256) void gap_kernel(const float* __restrict__ x,
                                                  float* __restrict__ y) {
    const int row  = (blockIdx.x << 2) | (threadIdx.x >> 6); // 4 waves/block
    const int lane = threadIdx.x & 63;
    const float4* xr = (const float4*)(x + (size_t)row * HWSZ);

    float s = 0.f;
#pragma unroll
    for (int it = 0; it < 12; ++it) {
        float4 v = xr[lane + (it << 6)];
        s += (v.x + v.y) + (v.z + v.w);
    }
    if (lane < 16) {
        float4 v = xr[768 + lane];
        s += (v.x + v.y) + (v.z + v.w);
    }
#pragma unroll
    for (int off = 32; off > 0; off >>= 1) s += __shfl_down(s, off);
    if (lane == 0) y[row] = s * (1.0f / 3136.0f);
}

// ---------------------------------------------------------------------------
// Kernel 2: h = gelu(y @ W1). Block=(jc,b): 64 cols, 4-way split-K, LDS reduce.
// ---------------------------------------------------------------------------
__global__ __launch_bounds__(256) void fc1_kernel(const float* __restrict__ y,
                                                  const float* __restrict__ W1,
                                                  float* __restrict__ h) {
    const int jc = blockIdx.x;   // 0..7
    const int b  = blockIdx.y;   // 0..31
    const int t  = threadIdx.x;

    __shared__ float sy[NC];
    __shared__ float part[256];
    for (int i = t; i < NC; i += 256) sy[i] = y[b * NC + i];
    __syncthreads();

    const int j  = jc * 64 + (t & 63);
    const int ks = (t >> 6) * 256;
    const float* w = W1 + (size_t)ks * NHID + j;

    float a0 = 0.f, a1 = 0.f, a2 = 0.f, a3 = 0.f;
    for (int c = 0; c < 256; c += 4) {
        a0 += sy[ks + c + 0] * w[(size_t)(c + 0) * NHID];
        a1 += sy[ks + c + 1] * w[(size_t)(c + 1) * NHID];
        a2 += sy[ks + c + 2] * w[(size_t)(c + 2) * NHID];
        a3 += sy[ks + c + 3] * w[(size_t)(c + 3) * NHID];
    }
    part[t] = (a0 + a1) + (a2 + a3);
    __syncthreads();
    if (t < 64) {
        float v = part[t] + part[t + 64] + part[t + 128] + part[t + 192];
        h[b * NHID + jc * 64 + t] = gelu_exact(v);
    }
}

// ---------------------------------------------------------------------------
// Kernel 3: yp = gelu(h @ W2). Block=(cc,b): 64 cols, 4-way split-K.
// ---------------------------------------------------------------------------
__global__ __launch_bounds__(256) void fc2_kernel(const float* __restrict__ h,
                                                  const float* __restrict__ W2,
                                                  float* __restrict__ yp) {
    const int cc = blockIdx.x;   // 0..15
    const int b  = blockIdx.y;
    const int t  = threadIdx.x;

    __shared__ float sh[NHID];
    __shared__ float part[256];
    for (int i = t; i < NHID; i += 256) sh[i] = h[b * NHID + i];
    __syncthreads();

    const int c  = cc * 64 + (t & 63);
    const int js = (t >> 6) * 128;
    const float* w = W2 + (size_t)js * NC + c;

    float a0 = 0.f, a1 = 0.f, a2 = 0.f, a3 = 0.f;
    for (int jj = 0; jj < 128; jj += 4) {
        a0 += sh[js + jj + 0] * w[(size_t)(jj + 0) * NC];
        a1 += sh[js + jj + 1] * w[(size_t)(jj + 1) * NC];
        a2 += sh[js + jj + 2] * w[(size_t)(jj + 2) * NC];
        a3 += sh[js + jj + 3] * w[(size_t)(jj + 3) * NC];
    }
    part[t] = (a0 + a1) + (a2 + a3);
    __syncthreads();
    if (t < 64) {
        float v = part[t] + part[t + 64] + part[t + 128] + part[t + 192];
        yp[b * NC + cc * 64 + t] = gelu_exact(v);
    }
}

// ---------------------------------------------------------------------------
// Kernel 4: A = yp@WA+bA, Bv = yp@WB+bB only (no map). AB[b][0..55]=A,
// AB[b][64..119]=Bv. 4-acc ILP in the K loops.
// ---------------------------------------------------------------------------
__global__ __launch_bounds__(256) void ab_kernel(
    const float* __restrict__ yp, const float* __restrict__ WA,
    const float* __restrict__ bA, const float* __restrict__ WB,
    const float* __restrict__ bB, float* __restrict__ AB) {
    const int b = blockIdx.x;
    const int t = threadIdx.x;

    __shared__ float sp[NC];
    __shared__ float partA[256];
    __shared__ float partB[256];
    for (int i = t; i < NC; i += 256) sp[i] = yp[b * NC + i];
    __syncthreads();

    const int i  = t & 63;
    const int ks = (t >> 6) * 256;
    float a0 = 0.f, a1 = 0.f, a2 = 0.f, a3 = 0.f;
    float b0 = 0.f, b1 = 0.f, b2 = 0.f, b3 = 0.f;
    if (i < NH) {
        const float* wa = WA + (size_t)ks * NH + i;
        const float* wb = WB + (size_t)ks * NW + i;
        for (int c = 0; c < 256; c += 4) {
            a0 += sp[ks + c + 0] * wa[(size_t)(c + 0) * NH];
            a1 += sp[ks + c + 1] * wa[(size_t)(c + 1) * NH];
            a2 += sp[ks + c + 2] * wa[(size_t)(c + 2) * NH];
            a3 += sp[ks + c + 3] * wa[(size_t)(c + 3) * NH];
            b0 += sp[ks + c + 0] * wb[(size_t)(c + 0) * NW];
            b1 += sp[ks + c + 1] * wb[(size_t)(c + 1) * NW];
            b2 += sp[ks + c + 2] * wb[(size_t)(c + 2) * NW];
            b3 += sp[ks + c + 3] * wb[(size_t)(c + 3) * NW];
        }
    }
    partA[t] = (a0 + a1) + (a2 + a3);
    partB[t] = (b0 + b1) + (b2 + b3);
    __syncthreads();
    if (t < NH) {
        AB[b * 128 + t] = bA[t] + partA[t] + partA[t + 64] + partA[t + 128] + partA[t + 192];
        AB[b * 128 + 64 + t] = bB[t] + partB[t] + partB[t + 64] + partB[t + 128] + partB[t + 192];
    }
}

// ---------------------------------------------------------------------------
// Kernel 5: out[b,ch,i,j] = sigmoid(A[b,i]*Bv[b,j]), 16 channels per block.
// Sigmoid map computed once into registers, written 16x (nontemporal).
// Each float4 stays inside one row (56 % 4 == 0, 14 float4/row).
// ---------------------------------------------------------------------------
__global__ __launch_bounds__(256) void bcast_kernel(const float* __restrict__ AB,
                                                    float* __restrict__ out) {
    const int blk = blockIdx.x;      // 32 b * 64 chunks
    const int b = blk >> 6;
    const int cchunk = blk & 63;
    const int t = threadIdx.x;

    __shared__ float sA[NH];
    __shared__ float sB[NW];
    if (t < NH) sA[t] = AB[b * 128 + t];
    else if (t >= 64 && t < 64 + NW) sB[t - 64] = AB[b * 128 + t];
    __syncthreads();

    nfloat4 v[4];
#pragma unroll
    for (int it = 0; it < 4; ++it) {
        const int idx = t + it * 256;          // float4 index in the 784-map
        if (idx < HW4) {
            const int r  = idx / 14;
            const int cb = (idx - r * 14) * 4;
            const float a = sA[r];
            nfloat4 q;
            q.x = 1.0f / (1.0f + expf(-(a * sB[cb + 0])));
            q.y = 1.0f / (1.0f + expf(-(a * sB[cb + 1])));
            q.z = 1.0f / (1.0f + expf(-(a * sB[cb + 2])));
            q.w = 1.0f / (1.0f + expf(-(a * sB[cb + 3])));
            v[it] = q;
        }
    }

    const size_t base = ((size_t)b * NC + (size_t)cchunk * 16) * HW4; // float4 units
#pragma unroll
    for (int ch = 0; ch < 16; ++ch) {
        nfloat4* orow = (nfloat4*)out + base + (size_t)ch * HW4;
#pragma unroll
        for (int it = 0; it < 4; ++it) {
            const int idx = t + it * 256;
            if (idx < HW4) __builtin_nontemporal_store(v[it], &orow[idx]);
        }
    }
}

// ---------------------------------------------------------------------------
extern "C" void kernel_launch(void* const* d_in, const int* in_sizes, int n_in,
                              void* d_out, int out_size, void* d_ws, size_t ws_size,
                              hipStream_t stream) {
    const float* x  = (const float*)d_in[0];
    const float* W1 = (const float*)d_in[1];
    const float* W2 = (const float*)d_in[2];
    const float* WA = (const float*)d_in[3];
    const float* bA = (const float*)d_in[4];
    const float* WB = (const float*)d_in[5];
    const float* bB = (const float*)d_in[6];
    float* out = (float*)d_out;

    float* y  = (float*)d_ws;            // BATCH*NC floats; yp aliases y
    float* yp = y;
    float* h  = y + BATCH * NC;          // BATCH*NHID floats
    float* AB = h + BATCH * NHID;        // BATCH*128 floats

    gap_kernel<<<BATCH * NC / 4, 256, 0, stream>>>(x, y);
    fc1_kernel<<<dim3(NHID / 64, BATCH), 256, 0, stream>>>(y, W1, h);
    fc2_kernel<<<dim3(NC / 64, BATCH), 256, 0, stream>>>(h, W2, yp);
    ab_kernel<<<BATCH, 256, 0, stream>>>(yp, WA, bA, WB, bB, AB);
    bcast_kernel<<<BATCH * (NC / 16), 256, 0, stream>>>(AB, out);
}

// Round 8
// 162.526 us; speedup vs baseline: 2.4002x; 1.1167x over previous
//
#include <hip/hip_runtime.h>
#include <math.h>

#define BATCH 32
#define NC    1024
#define NHID  512
#define NH    56
#define NW    56
#define HWSZ  3136   // 56*56
#define HW4   784    // HWSZ/4 (= 56 rows * 14 float4/row)

typedef float nfloat4 __attribute__((ext_vector_type(4)));

__device__ __forceinline__ float gelu_exact(float x) {
    return 0.5f * x * (1.0f + erff(x * 0.7071067811865476f));
}

// ---------------------------------------------------------------------------
// Kernel 1: GAP. One WAVE per (b,c) row — no LDS, no barriers. NT loads.
// ---------------------------------------------------------------------------
__global__ __launch_bounds__(256) void gap_kernel(const float* __restrict__ x,
                                                  float* __restrict__ y) {
    const int row  = (blockIdx.x << 2) | (threadIdx.x >> 6); // 4 waves/block
    const int lane = threadIdx.x & 63;
    const nfloat4* xr = (const nfloat4*)(x + (size_t)row * HWSZ);

    float s = 0.f;
#pragma unroll
    for (int it = 0; it < 12; ++it) {
        nfloat4 v = __builtin_nontemporal_load(xr + lane + (it << 6));
        s += (v.x + v.y) + (v.z + v.w);
    }
    if (lane < 16) {
        nfloat4 v = __builtin_nontemporal_load(xr + 768 + lane);
        s += (v.x + v.y) + (v.z + v.w);
    }
#pragma unroll
    for (int off = 32; off > 0; off >>= 1) s += __shfl_down(s, off);
    if (lane == 0) y[row] = s * (1.0f / 3136.0f);
}

// ---------------------------------------------------------------------------
// Kernel 2: h = gelu(y @ W1). Block=(jc,b): 64 cols via 16 lanes x float4,
// 16-way split-K (64 c-iters/thread), float4 weight loads.
// ---------------------------------------------------------------------------
__global__ __launch_bounds__(256) void fc1_kernel(const float* __restrict__ y,
                                                  const float* __restrict__ W1,
                                                  float* __restrict__ h) {
    const int jc = blockIdx.x;   // 0..7
    const int b  = blockIdx.y;   // 0..31
    const int t  = threadIdx.x;

    __shared__ float sy[NC];
    __shared__ nfloat4 part[256];
    for (int i = t; i < NC; i += 256) sy[i] = y[b * NC + i];
    __syncthreads();

    const int lane4 = t & 15;
    const int j0 = jc * 64 + lane4 * 4;
    const int ks = (t >> 4) * 64;            // 16 K-slices of 64

    nfloat4 acc0 = {0.f, 0.f, 0.f, 0.f};
    nfloat4 acc1 = {0.f, 0.f, 0.f, 0.f};
    const float* wbase = W1 + (size_t)ks * NHID + j0;
#pragma unroll 8
    for (int c = 0; c < 64; c += 2) {
        nfloat4 w0 = *(const nfloat4*)(wbase + (size_t)(c + 0) * NHID);
        nfloat4 w1 = *(const nfloat4*)(wbase + (size_t)(c + 1) * NHID);
        acc0 += sy[ks + c + 0] * w0;
        acc1 += sy[ks + c + 1] * w1;
    }
    part[t] = acc0 + acc1;
    __syncthreads();
    if (t < 16) {
        nfloat4 s = part[t];
#pragma unroll
        for (int g = 1; g < 16; ++g) s += part[g * 16 + t];
        float* hp = h + b * NHID + jc * 64 + t * 4;
        hp[0] = gelu_exact(s.x);
        hp[1] = gelu_exact(s.y);
        hp[2] = gelu_exact(s.z);
        hp[3] = gelu_exact(s.w);
    }
}

// ---------------------------------------------------------------------------
// Kernel 3: yp = gelu(h @ W2). Block=(cc,b): 64 cols via 16 lanes x float4,
// 16-way split-K (32 c-iters/thread).
// ---------------------------------------------------------------------------
__global__ __launch_bounds__(256) void fc2_kernel(const float* __restrict__ h,
                                                  const float* __restrict__ W2,
                                                  float* __restrict__ yp) {
    const int cc = blockIdx.x;   // 0..15
    const int b  = blockIdx.y;
    const int t  = threadIdx.x;

    __shared__ float sh[NHID];
    __shared__ nfloat4 part[256];
    for (int i = t; i < NHID; i += 256) sh[i] = h[b * NHID + i];
    __syncthreads();

    const int lane4 = t & 15;
    const int c0 = cc * 64 + lane4 * 4;
    const int js = (t >> 4) * 32;            // 16 K-slices of 32

    nfloat4 acc0 = {0.f, 0.f, 0.f, 0.f};
    nfloat4 acc1 = {0.f, 0.f, 0.f, 0.f};
    const float* wbase = W2 + (size_t)js * NC + c0;
#pragma unroll 8
    for (int jj = 0; jj < 32; jj += 2) {
        nfloat4 w0 = *(const nfloat4*)(wbase + (size_t)(jj + 0) * NC);
        nfloat4 w1 = *(const nfloat4*)(wbase + (size_t)(jj + 1) * NC);
        acc0 += sh[js + jj + 0] * w0;
        acc1 += sh[js + jj + 1] * w1;
    }
    part[t] = acc0 + acc1;
    __syncthreads();
    if (t < 16) {
        nfloat4 s = part[t];
#pragma unroll
        for (int g = 1; g < 16; ++g) s += part[g * 16 + t];
        float* pp = yp + b * NC + cc * 64 + t * 4;
        pp[0] = gelu_exact(s.x);
        pp[1] = gelu_exact(s.y);
        pp[2] = gelu_exact(s.z);
        pp[3] = gelu_exact(s.w);
    }
}

// ---------------------------------------------------------------------------
// Kernel 4: A = yp@WA+bA, Bv = yp@WB+bB. 512 threads, 8-way split-K.
// AB[b][0..55]=A, AB[b][64..119]=Bv.
// ---------------------------------------------------------------------------
__global__ __launch_bounds__(512) void ab_kernel(
    const float* __restrict__ yp, const float* __restrict__ WA,
    const float* __restrict__ bA, const float* __restrict__ WB,
    const float* __restrict__ bB, float* __restrict__ AB) {
    const int b = blockIdx.x;
    const int t = threadIdx.x;

    __shared__ float sp[NC];
    __shared__ float partA[512];
    __shared__ float partB[512];
    for (int i = t; i < NC; i += 512) sp[i] = yp[b * NC + i];
    __syncthreads();

    const int i  = t & 63;
    const int ks = (t >> 6) * 128;           // 8 K-slices of 128
    float a0 = 0.f, a1 = 0.f, a2 = 0.f, a3 = 0.f;
    float b0 = 0.f, b1 = 0.f, b2 = 0.f, b3 = 0.f;
    if (i < NH) {
        const float* wa = WA + (size_t)ks * NH + i;
        const float* wb = WB + (size_t)ks * NW + i;
        for (int c = 0; c < 128; c += 4) {
            a0 += sp[ks + c + 0] * wa[(size_t)(c + 0) * NH];
            a1 += sp[ks + c + 1] * wa[(size_t)(c + 1) * NH];
            a2 += sp[ks + c + 2] * wa[(size_t)(c + 2) * NH];
            a3 += sp[ks + c + 3] * wa[(size_t)(c + 3) * NH];
            b0 += sp[ks + c + 0] * wb[(size_t)(c + 0) * NW];
            b1 += sp[ks + c + 1] * wb[(size_t)(c + 1) * NW];
            b2 += sp[ks + c + 2] * wb[(size_t)(c + 2) * NW];
            b3 += sp[ks + c + 3] * wb[(size_t)(c + 3) * NW];
        }
    }
    partA[t] = (a0 + a1) + (a2 + a3);
    partB[t] = (b0 + b1) + (b2 + b3);
    __syncthreads();
    if (t < NH) {
        float sa = bA[t], sb = bB[t];
#pragma unroll
        for (int g = 0; g < 8; ++g) {
            sa += partA[g * 64 + t];
            sb += partB[g * 64 + t];
        }
        AB[b * 128 + t] = sa;
        AB[b * 128 + 64 + t] = sb;
    }
}

// ---------------------------------------------------------------------------
// Kernel 5: out[b,ch,i,j] = sigmoid(A[b,i]*Bv[b,j]), 16 channels per block.
// Map computed once in registers, written 16x with NT stores.
// ---------------------------------------------------------------------------
__global__ __launch_bounds__(256) void bcast_kernel(const float* __restrict__ AB,
                                                    float* __restrict__ out) {
    const int blk = blockIdx.x;      // 32 b * 64 chunks
    const int b = blk >> 6;
    const int cchunk = blk & 63;
    const int t = threadIdx.x;

    __shared__ float sA[NH];
    __shared__ float sB[NW];
    if (t < NH) sA[t] = AB[b * 128 + t];
    else if (t >= 64 && t < 64 + NW) sB[t - 64] = AB[b * 128 + t];
    __syncthreads();

    nfloat4 v[4];
#pragma unroll
    for (int it = 0; it < 4; ++it) {
        const int idx = t + it * 256;          // float4 index in the 784-map
        if (idx < HW4) {
            const int r  = idx / 14;
            const int cb = (idx - r * 14) * 4;
            const float a = sA[r];
            nfloat4 q;
            q.x = 1.0f / (1.0f + expf(-(a * sB[cb + 0])));
            q.y = 1.0f / (1.0f + expf(-(a * sB[cb + 1])));
            q.z = 1.0f / (1.0f + expf(-(a * sB[cb + 2])));
            q.w = 1.0f / (1.0f + expf(-(a * sB[cb + 3])));
            v[it] = q;
        }
    }

    const size_t base = ((size_t)b * NC + (size_t)cchunk * 16) * HW4; // float4 units
#pragma unroll
    for (int ch = 0; ch < 16; ++ch) {
        nfloat4* orow = (nfloat4*)out + base + (size_t)ch * HW4;
#pragma unroll
        for (int it = 0; it < 4; ++it) {
            const int idx = t + it * 256;
            if (idx < HW4) __builtin_nontemporal_store(v[it], &orow[idx]);
        }
    }
}

// ---------------------------------------------------------------------------
extern "C" void kernel_launch(void* const* d_in, const int* in_sizes, int n_in,
                              void* d_out, int out_size, void* d_ws, size_t ws_size,
                              hipStream_t stream) {
    const float* x  = (const float*)d_in[0];
    const float* W1 = (const float*)d_in[1];
    const float* W2 = (const float*)d_in[2];
    const float* WA = (const float*)d_in[3];
    const float* bA = (const float*)d_in[4];
    const float* WB = (const float*)d_in[5];
    const float* bB = (const float*)d_in[6];
    float* out = (float*)d_out;

    float* y  = (float*)d_ws;            // BATCH*NC floats; yp aliases y
    float* yp = y;
    float* h  = y + BATCH * NC;          // BATCH*NHID floats
    float* AB = h + BATCH * NHID;        // BATCH*128 floats

    gap_kernel<<<BATCH * NC / 4, 256, 0, stream>>>(x, y);
    fc1_kernel<<<dim3(NHID / 64, BATCH), 256, 0, stream>>>(y, W1, h);
    fc2_kernel<<<dim3(NC / 64, BATCH), 256, 0, stream>>>(h, W2, yp);
    ab_kernel<<<BATCH, 512, 0, stream>>>(yp, WA, bA, WB, bB, AB);
    bcast_kernel<<<BATCH * (NC / 16), 256, 0, stream>>>(AB, out);
}